// Round 8
// baseline (476.109 us; speedup 1.0000x reference)
//
#include <hip/hip_runtime.h>

#define N_ENTITIES 200000
#define N_ITEMS    100000
#define DIM        64
#define N_EDGES    1500000
#define K_EDGES    256
#define K_ITEMS    100
// 1 / (2 * sqrt(32))  (mean over 2 heads of per-head 1/sqrt(Dk))
#define SCALE      0.08838834764831845f

#define CAND_CAP   8192
#define NBLK3      1024                          // edge_pass3 grid (partial hists)

typedef unsigned long long u64;

// NOTE (round-0): fp16/bf16 storage of proj is FORBIDDEN (ordered top-100 item
// list; adjacent gaps ~8e-6; fp16 error 2.7e-6 -> rank flips). f32 only.
// NOTE (round-2): 16-edges/iter predicated widening in a CSR wave is a VALU
// loss. (Moot now: edge-centric pass has zero masked slots.)
// NOTE (rounds 3-7, the atomic saga): gfx950 global atomics execute at the
// memory-side coherence point regardless of scope/sc-bits/replicas
// (WRITE_SIZE byte-identical across agent/workgroup/no-sc1; ~32B per RMW).
//   - NON-RETURNING atomics pipeline freely: removing 1.76M of them (r7)
//     changed total by 0.03us. They are effectively FREE in memory-bound
//     kernels.
//   - RETURNING atomics are a hard drain: 1.5M of them pinned proj_kernel
//     at ~105us (GEMM alone ~25-30us) across FIVE implementations.
// Optimization rule: never block on an atomic return; restructure the
// algorithm (here: edge-centric, no CSR) instead of tuning atomic flavor.

// ---- monotonic float<->u32 key (order-preserving, total order) ----
__device__ __forceinline__ unsigned fkey(float x) {
    unsigned u = __float_as_uint(x);
    return (u & 0x80000000u) ? ~u : (u | 0x80000000u);
}
__device__ __forceinline__ float funkey(unsigned k) {
    return (k & 0x80000000u) ? __uint_as_float(k & 0x7fffffffu)
                             : __uint_as_float(~k);
}

// serial 256-bin select: largest bin b with count(>b) < Keff <= count(>=b).
__device__ __forceinline__ unsigned select_digit(const unsigned* __restrict__ hist,
                                                 unsigned Keff, unsigned* above) {
    unsigned cum = 0;
    int b = 255;
    for (; b > 0; --b) {
        unsigned hb = hist[b];
        if (cum + hb >= Keff) break;
        cum += hb;
    }
    *above = cum;
    return (unsigned)b;
}

// ---- proj = emb @ W_Q, fused with degree count (NON-returning float atomic
// into nd[h].y; free per the r6/r7 evidence). No rank, no CSR machinery.
__global__ __launch_bounds__(256) void proj_kernel(const float* __restrict__ emb,
                                                   const float* __restrict__ W,
                                                   float* __restrict__ proj,
                                                   const int* __restrict__ head,
                                                   float* __restrict__ ndf) {
    int e = blockIdx.x * blockDim.x + threadIdx.x;   // 12500*256 = 3.2M >= N_EDGES
    if (e < N_EDGES) atomicAdd(&ndf[2 * head[e] + 1], 1.0f);   // result unused -> no-return form

    __shared__ float part[4][16][64];
    const int t = threadIdx.x;
    const int c = t & 63;
    const int q = __builtin_amdgcn_readfirstlane(t >> 6);

    float Wreg[16];
#pragma unroll
    for (int j = 0; j < 16; ++j) Wreg[j] = W[(q * 16 + j) * 64 + c];

    const int base = blockIdx.x * 16;   // 200000 = 12500 * 16, exact
    const float* erow = emb + (size_t)base * 64 + q * 16;

    float acc[16];
#pragma unroll
    for (int r = 0; r < 16; ++r) acc[r] = 0.f;
#pragma unroll
    for (int r = 0; r < 16; ++r) {
#pragma unroll
        for (int j = 0; j < 16; ++j)
            acc[r] += erow[r * 64 + j] * Wreg[j];
    }
#pragma unroll
    for (int r = 0; r < 16; ++r) part[q][r][c] = acc[r];
    __syncthreads();
#pragma unroll
    for (int it = 0; it < 4; ++it) {
        int oi = t + it * 256;
        int r = oi >> 6, cc = oi & 63;
        float s = part[0][r][cc] + part[1][r][cc] + part[2][r][cc] + part[3][r][cc];
        proj[(size_t)(base + r) * 64 + cc] = s;
    }
}

// ---- edge-centric main pass: one wave per 8 edges (16 lanes per edge-pair).
// Zero masked work (1.5M = 187500 waves * 8 exactly). Per edge: gather
// proj[head], proj[tail], rel; dot; streaming logits write; NON-returning
// atomics for denom (nd.x) and item sums (sumI). Replaces scan1+scan23+
// scatter+node_pass and the entire CSR build.
__global__ __launch_bounds__(256) void edge_main(const float4* __restrict__ proj4,
                                                 const float4* __restrict__ rel4,
                                                 const int* __restrict__ head,
                                                 const int* __restrict__ tail,
                                                 const int* __restrict__ etype,
                                                 float* __restrict__ logits,
                                                 float* __restrict__ ndf,
                                                 float* __restrict__ sumI) {
    int wave = (blockIdx.x * blockDim.x + threadIdx.x) >> 6;   // 187500 waves, exact
    int lane = threadIdx.x & 63;
    int slot = lane >> 4, sl = lane & 15;
    int ea = wave * 8 + slot, eb = ea + 4;

    int ha  = head[ea],  hb  = head[eb];
    int tta = tail[ea],  ttb = tail[eb];
    int ria = etype[ea] - 1, rib = etype[eb] - 1;

    float4 pha = proj4[(size_t)ha  * 16 + sl];
    float4 pta = proj4[(size_t)tta * 16 + sl];
    float4 qra = rel4[(size_t)ria * 16 + sl];
    float4 phb = proj4[(size_t)hb  * 16 + sl];
    float4 ptb = proj4[(size_t)ttb * 16 + sl];
    float4 qrb = rel4[(size_t)rib * 16 + sl];

    float xa = pha.x * pta.x * qra.x + pha.y * pta.y * qra.y
             + pha.z * pta.z * qra.z + pha.w * pta.w * qra.w;
    float xb = phb.x * ptb.x * qrb.x + phb.y * ptb.y * qrb.y
             + phb.z * ptb.z * qrb.z + phb.w * ptb.w * qrb.w;
    xa += __shfl_xor(xa, 1, 64);  xb += __shfl_xor(xb, 1, 64);
    xa += __shfl_xor(xa, 2, 64);  xb += __shfl_xor(xb, 2, 64);
    xa += __shfl_xor(xa, 4, 64);  xb += __shfl_xor(xb, 4, 64);
    xa += __shfl_xor(xa, 8, 64);  xb += __shfl_xor(xb, 8, 64);

    if (sl == 0) {
        float lga = xa * SCALE, lgb = xb * SCALE;
        logits[ea] = lga;
        logits[eb] = lgb;
        atomicAdd(&ndf[2 * ha], __expf(lga));     // non-returning
        atomicAdd(&ndf[2 * hb], __expf(lgb));
        if (ha  < N_ITEMS) atomicAdd(&sumI[ha],  lga);
        if (tta < N_ITEMS) atomicAdd(&sumI[tta], lga);
        if (hb  < N_ITEMS) atomicAdd(&sumI[hb],  lgb);
        if (ttb < N_ITEMS) atomicAdd(&sumI[ttb], lgb);
    }
}

// ---- scores + gumbel keys + item keys + partial hists (stores, no atomics) ----
__global__ __launch_bounds__(256) void edge_pass3(const float* __restrict__ logits,
                           const int* __restrict__ head,
                           const float* __restrict__ ndf, const float* __restrict__ noise_u,
                           const float* __restrict__ sumI,
                           float* __restrict__ out_scores, unsigned* __restrict__ keysE,
                           unsigned* __restrict__ keysI, unsigned* __restrict__ histB) {
    __shared__ unsigned hh[512];   // [0..255]=edge bins, [256..511]=item bins
    for (int j = threadIdx.x; j < 512; j += blockDim.x) hh[j] = 0;
    __syncthreads();

    const int stride = NBLK3 * 256;
    for (int i = blockIdx.x * blockDim.x + threadIdx.x; i < N_EDGES; i += stride) {
        float lg = logits[i];
        float2 dd = ((const float2*)ndf)[head[i]];   // (denom, deg)
        float score = __expf(lg) / dd.x * dd.y;
        out_scores[i] = score;
        float noise = -logf(-logf(noise_u[i]));   // library logf: accurate near u->1
        unsigned k = fkey(score + noise);
        keysE[i] = k;
        atomicAdd(&hh[k >> 24], 1u);
        if (i < N_ITEMS) {
            unsigned ki = fkey(sumI[i]);
            keysI[i] = ki;
            atomicAdd(&hh[256 + (ki >> 24)], 1u);
        }
    }
    __syncthreads();
    unsigned* row = histB + (size_t)blockIdx.x * 512;
    for (int j = threadIdx.x; j < 512; j += blockDim.x) row[j] = hh[j];
}

// ---- fold partial hists: hists[bin] = sum_b histB[b][bin]; 512 blocks ----
__global__ void reduce_hist_kernel(const unsigned* __restrict__ histB,
                                   unsigned* __restrict__ hists) {
    const int bin = blockIdx.x;          // 0..511
    unsigned s = 0;
    for (int r = threadIdx.x; r < NBLK3; r += 64)
        s += histB[(size_t)r * 512 + bin];
#pragma unroll
    for (int off = 1; off < 64; off <<= 1) s += __shfl_xor(s, off, 64);
    if (threadIdx.x == 0) hists[bin] = s;
}

// ---- collect candidates >= 8-bit (sign+exponent) threshold ----
// Edge keys ~ gumbel tail -> ~1.4k candidates in/above the boundary exponent
// bin; item keys ~ normal tail -> ~200. CAND_CAP=8192 gives 3-5x margin.
__global__ void collect_kernel(const unsigned* __restrict__ keysE,
                               const unsigned* __restrict__ keysI,
                               const unsigned* __restrict__ hists,
                               unsigned* __restrict__ counters, unsigned* __restrict__ cand) {
    const int y = blockIdx.y;
    const unsigned* keys = y ? keysI : keysE;
    const int n = y ? N_ITEMS : N_EDGES;
    const unsigned K = y ? K_ITEMS : K_EDGES;
    const unsigned* H = hists + (size_t)y * 256;
    unsigned aboveA;
    unsigned binA = select_digit(H, K, &aboveA);
    const unsigned T = binA << 24;
    unsigned* cd = cand + (size_t)y * 2 * CAND_CAP;

    int i = blockIdx.x * blockDim.x + threadIdx.x;
    int stride = gridDim.x * blockDim.x;
    for (; i < n; i += stride) {
        unsigned k = keys[i];
        if (k >= T) {
            unsigned p = atomicAdd(&counters[y], 1u);   // rare (~1.6k total): fine
            if (p < (unsigned)CAND_CAP) { cd[2 * p] = k; cd[2 * p + 1] = (unsigned)i; }
        }
    }
}

// ---- exact rank among candidates (key desc, index asc); 2 blocks (y) ----
__global__ void final_topk_kernel(const unsigned* __restrict__ cand,
                                  const unsigned* __restrict__ counters,
                                  float* __restrict__ out_topkv, float* __restrict__ out_topki,
                                  float* __restrict__ out_itemv, float* __restrict__ out_itemi) {
    __shared__ unsigned sk[CAND_CAP];
    __shared__ unsigned si[CAND_CAP];
    const int y = blockIdx.x;
    const int K = y ? K_ITEMS : K_EDGES;
    float* outv = y ? out_itemv : out_topkv;
    float* outi = y ? out_itemi : out_topki;
    const unsigned* cd = cand + (size_t)y * 2 * CAND_CAP;
    unsigned m = counters[y];
    if (m > (unsigned)CAND_CAP) m = CAND_CAP;
    for (unsigned i = threadIdx.x; i < m; i += blockDim.x) {
        sk[i] = cd[2 * i];
        si[i] = cd[2 * i + 1];
    }
    __syncthreads();
    for (unsigned i = threadIdx.x; i < m; i += blockDim.x) {
        unsigned ki = sk[i], xi = si[i];
        int r = 0;
        for (unsigned j = 0; j < m; ++j) {
            unsigned kj = sk[j];
            if (kj > ki || (kj == ki && si[j] < xi)) r++;
        }
        if (r < K) {
            outv[r] = funkey(ki);
            outi[r] = (float)xi;
        }
    }
}

extern "C" void kernel_launch(void* const* d_in, const int* in_sizes, int n_in,
                              void* d_out, int out_size, void* d_ws, size_t ws_size,
                              hipStream_t stream) {
    (void)in_sizes; (void)n_in; (void)out_size; (void)ws_size;
    const float* emb    = (const float*)d_in[0];
    const float* W      = (const float*)d_in[1];
    const float* rel    = (const float*)d_in[2];
    const float* noise  = (const float*)d_in[3];
    const int*   eidx   = (const int*)d_in[4];
    const int*   etype  = (const int*)d_in[5];
    const int* head = eidx;
    const int* tail = eidx + N_EDGES;

    float* out        = (float*)d_out;
    float* out_scores = out;
    float* out_topkv  = out + N_EDGES;
    float* out_topki  = out + N_EDGES + K_EDGES;
    float* out_itemv  = out + N_EDGES + 2 * K_EDGES;
    float* out_itemi  = out + N_EDGES + 2 * K_EDGES + K_ITEMS;

    float* ws = (float*)d_ws;
    size_t o = 0;
    float*    proj    = ws + o;               o += (size_t)N_ENTITIES * DIM;
    float*    ndf     = ws + o;               o += 2 * (size_t)N_ENTITIES;  // memset begins
    float*    sumI    = ws + o;               o += N_ITEMS;
    unsigned* counters= (unsigned*)(ws + o);  o += 2;                       // memset ends
    float*    logits  = ws + o;               o += N_EDGES;
    unsigned* keysE   = (unsigned*)(ws + o);  o += N_EDGES;
    unsigned* keysI   = (unsigned*)(ws + o);  o += N_ITEMS;
    unsigned* histB   = (unsigned*)(ws + o);  o += (size_t)NBLK3 * 512;     // fully overwritten
    unsigned* hists   = (unsigned*)(ws + o);  o += 512;                     // fully overwritten
    unsigned* cand    = (unsigned*)(ws + o);  o += 2 * 2 * CAND_CAP;

    // zero: ndf + sumI + counters (contiguous, ~2MB)
    hipMemsetAsync(ndf, 0, (2 * (size_t)N_ENTITIES + N_ITEMS + 2) * 4, stream);
    // proj GEMM + non-returning degree count into nd[h].y
    hipLaunchKernelGGL(proj_kernel, dim3(12500), dim3(256), 0, stream,
                       emb, W, proj, head, ndf);
    // edge-centric main pass: logits + denom + item sums (all non-returning atomics)
    hipLaunchKernelGGL(edge_main, dim3(46875), dim3(256), 0, stream,
                       (const float4*)proj, (const float4*)rel, head, tail, etype,
                       logits, ndf, sumI);
    // scores + noisy keys + item keys + partial hists (stores only)
    hipLaunchKernelGGL(edge_pass3, dim3(NBLK3), dim3(256), 0, stream,
                       logits, head, ndf, noise, sumI,
                       out_scores, keysE, keysI, histB);
    // fold partial hists -> hists[512]
    hipLaunchKernelGGL(reduce_hist_kernel, dim3(512), dim3(64), 0, stream, histB, hists);
    // top-k: single 8-bit threshold collect + exact rank
    hipLaunchKernelGGL(collect_kernel, dim3(512, 2), dim3(256), 0, stream,
                       keysE, keysI, hists, counters, cand);
    hipLaunchKernelGGL(final_topk_kernel, dim3(2), dim3(1024), 0, stream,
                       cand, counters, out_topkv, out_topki, out_itemv, out_itemi);
}

// Round 9
// 437.120 us; speedup vs baseline: 1.0892x; 1.0892x over previous
//
#include <hip/hip_runtime.h>

#define N_ENTITIES 200000
#define N_ITEMS    100000
#define DIM        64
#define N_EDGES    1500000
#define K_EDGES    256
#define K_ITEMS    100
// 1 / (2 * sqrt(32))  (mean over 2 heads of per-head 1/sqrt(Dk))
#define SCALE      0.08838834764831845f

#define CAND_CAP   8192
#define NBLK3      1024      // edge_pass3 grid (partial hists)
#define NB1        256       // level-1 bucket blocks
#define EPB        5860      // edges per level-1 block (256*5860 >= 1.5M)
#define NBUCK      782       // head>>8 buckets (ceil(200000/256))
#define NSC        (NBUCK * NB1)   // 200192 scan elements (exactly 782*256)
#define L2CAP      2816      // max edges per bucket (mean 1918, sigma 44 -> +20 sigma)

typedef unsigned long long u64;

// NOTE (round-0): fp16/bf16 storage of proj is FORBIDDEN (ordered top-100 item
// list; adjacent gaps ~8e-6; fp16 error 2.7e-6 -> rank flips). f32 only.
// NOTE (rounds 3-8, the atomic saga, FINAL):
//   - gfx950 global atomics execute memory-side regardless of scope/sc-bits.
//   - NON-RETURNING global atomics are FREE (r7: removing 1.76M -> +0.03us).
//   - RETURNING global atomics drain ~50ns each chip-wide (1.5M = ~75us,
//     invariant across 5 implementations). NEVER build ranks with them.
//   - LDS returning atomics are cheap -> rank assignment belongs in LDS.
// NOTE (r8): edge-centric (no CSR) is traffic-bound at 467MB/2.9TB/s = 160us;
// node-major CSR amortizes the head row (-150MB) and keeps denom/head-sums
// in-register (-1.5M atomic signatures). CSR build must be atomic-free:
// two-level bucket sort (this round).
// NOTE (r0 vs r3 data): edge-ordered random 4B logits write costs only ~4us
// in node_pass (write churn absorbed) -- cheaper than slotmap machinery.

// ---- monotonic float<->u32 key (order-preserving, total order) ----
__device__ __forceinline__ unsigned fkey(float x) {
    unsigned u = __float_as_uint(x);
    return (u & 0x80000000u) ? ~u : (u | 0x80000000u);
}
__device__ __forceinline__ float funkey(unsigned k) {
    return (k & 0x80000000u) ? __uint_as_float(k & 0x7fffffffu)
                             : __uint_as_float(~k);
}

// serial 256-bin select: largest bin b with count(>b) < Keff <= count(>=b).
__device__ __forceinline__ unsigned select_digit(const unsigned* __restrict__ hist,
                                                 unsigned Keff, unsigned* above) {
    unsigned cum = 0;
    int b = 255;
    for (; b > 0; --b) {
        unsigned hb = hist[b];
        if (cum + hb >= Keff) break;
        cum += hb;
    }
    *above = cum;
    return (unsigned)b;
}

// ---- proj = emb @ W_Q. Pure GEMM: NO atomics (degree comes from the sort). ----
__global__ __launch_bounds__(256) void proj_kernel(const float* __restrict__ emb,
                                                   const float* __restrict__ W,
                                                   float* __restrict__ proj) {
    __shared__ float part[4][16][64];
    const int t = threadIdx.x;
    const int c = t & 63;
    const int q = __builtin_amdgcn_readfirstlane(t >> 6);

    float Wreg[16];
#pragma unroll
    for (int j = 0; j < 16; ++j) Wreg[j] = W[(q * 16 + j) * 64 + c];

    const int base = blockIdx.x * 16;   // 200000 = 12500 * 16, exact
    const float* erow = emb + (size_t)base * 64 + q * 16;

    float acc[16];
#pragma unroll
    for (int r = 0; r < 16; ++r) acc[r] = 0.f;
#pragma unroll
    for (int r = 0; r < 16; ++r) {
#pragma unroll
        for (int j = 0; j < 16; ++j)
            acc[r] += erow[r * 64 + j] * Wreg[j];
    }
#pragma unroll
    for (int r = 0; r < 16; ++r) part[q][r][c] = acc[r];
    __syncthreads();
#pragma unroll
    for (int it = 0; it < 4; ++it) {
        int oi = t + it * 256;
        int r = oi >> 6, cc = oi & 63;
        float s = part[0][r][cc] + part[1][r][cc] + part[2][r][cc] + part[3][r][cc];
        proj[(size_t)(base + r) * 64 + cc] = s;
    }
}

// ---- level-1 bucket histogram: per-block counts of head>>8 (stores only) ----
__global__ __launch_bounds__(256) void bhist_kernel(const int* __restrict__ head,
                                                    unsigned* __restrict__ off) {
    __shared__ unsigned lh[NBUCK];
    for (int k = threadIdx.x; k < NBUCK; k += 256) lh[k] = 0;
    __syncthreads();
    int base = blockIdx.x * EPB;
    int end = base + EPB; if (end > N_EDGES) end = N_EDGES;
    for (int e = base + threadIdx.x; e < end; e += 256)
        atomicAdd(&lh[(unsigned)head[e] >> 8], 1u);   // LDS atomic: cheap
    __syncthreads();
    for (int k = threadIdx.x; k < NBUCK; k += 256)
        off[(size_t)k * NB1 + blockIdx.x] = lh[k];
}

// ---- generic hierarchical exclusive scan over n = NSC elements (in-place) ----
__global__ void scanA_kernel(unsigned* __restrict__ a, unsigned* __restrict__ bsum) {
    __shared__ unsigned s[256];
    int t = threadIdx.x, i = blockIdx.x * 256 + t;
    unsigned v = a[i];                  // NSC = 782*256 exactly, no bounds check
    s[t] = v;
    __syncthreads();
    for (int off = 1; off < 256; off <<= 1) {
        unsigned x = s[t];
        unsigned y = (t >= off) ? s[t - off] : 0u;
        __syncthreads();
        s[t] = x + y;
        __syncthreads();
    }
    a[i] = s[t] - v;                    // block-local exclusive
    if (t == 255) bsum[blockIdx.x] = s[t];
}
__global__ __launch_bounds__(256) void scanB_kernel(const unsigned* __restrict__ bsum,
                                                    unsigned* __restrict__ a) {
    __shared__ unsigned part[4];
    const int b = blockIdx.x;
    const int t = threadIdx.x;
    unsigned s = 0;
    for (int j = t; j < b; j += 256) s += bsum[j];
#pragma unroll
    for (int off = 1; off < 64; off <<= 1) s += __shfl_xor(s, off, 64);
    if ((t & 63) == 0) part[t >> 6] = s;
    __syncthreads();
    unsigned prefix = part[0] + part[1] + part[2] + part[3];
    a[b * 256 + t] += prefix;
}

// ---- level-1 scatter: edges -> bucket-major rec2. Ranks via LDS atomics. ----
// rec = head(18b)<<45 | tail(18b)<<27 | rel(6b)<<21 | eid(21b)
__global__ __launch_bounds__(256) void bscat_kernel(const int* __restrict__ head,
                                                    const int* __restrict__ tail,
                                                    const int* __restrict__ etype,
                                                    const unsigned* __restrict__ off,
                                                    u64* __restrict__ rec2) {
    __shared__ unsigned lh[NBUCK];
    __shared__ unsigned loff[NBUCK];
    for (int k = threadIdx.x; k < NBUCK; k += 256) {
        lh[k] = 0;
        loff[k] = off[(size_t)k * NB1 + blockIdx.x];
    }
    __syncthreads();
    int base = blockIdx.x * EPB;
    int end = base + EPB; if (end > N_EDGES) end = N_EDGES;
    for (int e = base + threadIdx.x; e < end; e += 256) {
        unsigned h = (unsigned)head[e];
        unsigned bkt = h >> 8;
        unsigned r = atomicAdd(&lh[bkt], 1u);          // LDS returning atomic: cheap
        u64 R = ((u64)h << 45) | ((u64)(unsigned)tail[e] << 27)
              | ((u64)(unsigned)(etype[e] - 1) << 21) | (u64)(unsigned)e;
        rec2[loff[bkt] + r] = R;
    }
}

// ---- level-2: per-bucket CSR in LDS -> rec3 (coalesced) + start + degtot ----
__global__ __launch_bounds__(256) void csr_kernel(const u64* __restrict__ rec2,
                                                  const unsigned* __restrict__ off,
                                                  u64* __restrict__ rec3,
                                                  unsigned* __restrict__ start,
                                                  unsigned* __restrict__ degtot) {
    __shared__ u64 srec[L2CAP];
    __shared__ u64 sdst[L2CAP];
    __shared__ unsigned short srank[L2CAP];
    __shared__ unsigned lh[256];
    __shared__ unsigned lscan[256];
    const int bkt = blockIdx.x;
    const unsigned gstart = off[(size_t)bkt * NB1];
    const unsigned gend = (bkt == NBUCK - 1) ? (unsigned)N_EDGES
                                             : off[(size_t)(bkt + 1) * NB1];
    unsigned n = gend - gstart;
    if (n > L2CAP) n = L2CAP;   // statistically impossible; guards LDS only
    lh[threadIdx.x] = 0;
    __syncthreads();
    for (unsigned j = threadIdx.x; j < n; j += 256) {
        u64 R = rec2[gstart + j];
        srec[j] = R;
        unsigned hl = (unsigned)(R >> 45) & 255u;
        srank[j] = (unsigned short)atomicAdd(&lh[hl], 1u);
    }
    __syncthreads();
    // exclusive scan of per-entity counts
    unsigned v = lh[threadIdx.x];
    lscan[threadIdx.x] = v;
    __syncthreads();
    for (int o = 1; o < 256; o <<= 1) {
        unsigned x = lscan[threadIdx.x];
        unsigned y = (threadIdx.x >= o) ? lscan[threadIdx.x - o] : 0u;
        __syncthreads();
        lscan[threadIdx.x] = x + y;
        __syncthreads();
    }
    unsigned excl = lscan[threadIdx.x] - v;
    __syncthreads();
    lscan[threadIdx.x] = excl;
    const int h0 = bkt * 256;
    const int entCount = (N_ENTITIES - h0 < 256) ? (N_ENTITIES - h0) : 256;
    if ((int)threadIdx.x < entCount) {
        start[h0 + threadIdx.x] = gstart + excl;
        degtot[h0 + threadIdx.x] = v;
    }
    __syncthreads();
    // permute within LDS, then stream out coalesced
    for (unsigned j = threadIdx.x; j < n; j += 256) {
        u64 R = srec[j];
        unsigned hl = (unsigned)(R >> 45) & 255u;
        sdst[lscan[hl] + srank[j]] = R;
    }
    __syncthreads();
    for (unsigned j = threadIdx.x; j < n; j += 256) rec3[gstart + j] = sdst[j];
}

// ---- CSR main pass: one wave per head node, 8 edges/iter (2 per 16-lane slot).
// Head row loaded ONCE per node; denom + head-item-sum in-register; logits
// written EDGE-ordered (cheap, r0 evidence); sumI tail adds = non-returning
// global atomics (free, r7 evidence).
__global__ __launch_bounds__(256) void node_pass(const float4* __restrict__ proj4,
                                                 const float4* __restrict__ rel4,
                                                 const u64* __restrict__ rec,
                                                 const unsigned* __restrict__ start,
                                                 const unsigned* __restrict__ degtot,
                                                 float* __restrict__ logits,
                                                 float2* __restrict__ nd,
                                                 float* __restrict__ sumhead,
                                                 float* __restrict__ sumI) {
    int wave = (blockIdx.x * blockDim.x + threadIdx.x) >> 6;   // node id (grid exact)
    int lane = threadIdx.x & 63;
    int slot = lane >> 4, sl = lane & 15;
    unsigned s = start[wave], len = degtot[wave];
    float4 ph = proj4[(size_t)wave * 16 + sl];
    float dsum = 0.f, lsum = 0.f;
    for (unsigned k0 = 0; k0 < len; k0 += 8) {
        unsigned ka = k0 + slot, kb = ka + 4;
        bool va = (ka < len), vb = (kb < len);
        u64 Ra = rec[s + (va ? ka : 0u)];
        u64 Rb = rec[s + (vb ? kb : 0u)];
        unsigned ta = (unsigned)(Ra >> 27) & 0x3FFFFu, ria = ((unsigned)(Ra >> 21)) & 63u;
        unsigned tb = (unsigned)(Rb >> 27) & 0x3FFFFu, rib = ((unsigned)(Rb >> 21)) & 63u;
        unsigned ea = (unsigned)Ra & 0x1FFFFFu, eb = (unsigned)Rb & 0x1FFFFFu;
        float4 pa = proj4[(size_t)ta * 16 + sl];
        float4 qa = rel4[(size_t)ria * 16 + sl];
        float4 pb = proj4[(size_t)tb * 16 + sl];
        float4 qb = rel4[(size_t)rib * 16 + sl];
        float xa = ph.x * pa.x * qa.x + ph.y * pa.y * qa.y + ph.z * pa.z * qa.z + ph.w * pa.w * qa.w;
        float xb = ph.x * pb.x * qb.x + ph.y * pb.y * qb.y + ph.z * pb.z * qb.z + ph.w * pb.w * qb.w;
        xa += __shfl_xor(xa, 1, 64);  xb += __shfl_xor(xb, 1, 64);
        xa += __shfl_xor(xa, 2, 64);  xb += __shfl_xor(xb, 2, 64);
        xa += __shfl_xor(xa, 4, 64);  xb += __shfl_xor(xb, 4, 64);
        xa += __shfl_xor(xa, 8, 64);  xb += __shfl_xor(xb, 8, 64);
        if (sl == 0) {
            if (va) {
                float lg = xa * SCALE;
                logits[ea] = lg;
                dsum += __expf(lg);
                lsum += lg;
                if (ta < N_ITEMS) atomicAdd(&sumI[ta], lg);   // non-returning: free
            }
            if (vb) {
                float lg = xb * SCALE;
                logits[eb] = lg;
                dsum += __expf(lg);
                lsum += lg;
                if (tb < N_ITEMS) atomicAdd(&sumI[tb], lg);
            }
        }
    }
    dsum += __shfl_xor(dsum, 16, 64);
    dsum += __shfl_xor(dsum, 32, 64);
    lsum += __shfl_xor(lsum, 16, 64);
    lsum += __shfl_xor(lsum, 32, 64);
    if (lane == 0) {
        nd[wave] = make_float2(dsum, (float)len);
        sumhead[wave] = lsum;
    }
}

// ---- scores + gumbel keys + item keys + partial hists (stores, no atomics) ----
__global__ __launch_bounds__(256) void edge_pass3(const float* __restrict__ logits,
                           const int* __restrict__ head,
                           const float2* __restrict__ nd, const float* __restrict__ noise_u,
                           const float* __restrict__ sumhead, const float* __restrict__ sumI,
                           float* __restrict__ out_scores, unsigned* __restrict__ keysE,
                           unsigned* __restrict__ keysI, unsigned* __restrict__ histB) {
    __shared__ unsigned hh[512];   // [0..255]=edge bins, [256..511]=item bins
    for (int j = threadIdx.x; j < 512; j += blockDim.x) hh[j] = 0;
    __syncthreads();

    const int stride = NBLK3 * 256;
    for (int i = blockIdx.x * blockDim.x + threadIdx.x; i < N_EDGES; i += stride) {
        float lg = logits[i];
        float2 dd = nd[head[i]];   // (denom, deg); 1.6MB table -> cached
        float score = __expf(lg) / dd.x * dd.y;
        out_scores[i] = score;
        float noise = -logf(-logf(noise_u[i]));   // library logf: accurate near u->1
        unsigned k = fkey(score + noise);
        keysE[i] = k;
        atomicAdd(&hh[k >> 24], 1u);
        if (i < N_ITEMS) {
            unsigned ki = fkey(sumhead[i] + sumI[i]);
            keysI[i] = ki;
            atomicAdd(&hh[256 + (ki >> 24)], 1u);
        }
    }
    __syncthreads();
    unsigned* row = histB + (size_t)blockIdx.x * 512;
    for (int j = threadIdx.x; j < 512; j += blockDim.x) row[j] = hh[j];
}

// ---- fold partial hists: hists[bin] = sum_b histB[b][bin]; 512 blocks ----
__global__ void reduce_hist_kernel(const unsigned* __restrict__ histB,
                                   unsigned* __restrict__ hists) {
    const int bin = blockIdx.x;          // 0..511
    unsigned s = 0;
    for (int r = threadIdx.x; r < NBLK3; r += 64)
        s += histB[(size_t)r * 512 + bin];
#pragma unroll
    for (int off = 1; off < 64; off <<= 1) s += __shfl_xor(s, off, 64);
    if (threadIdx.x == 0) hists[bin] = s;
}

// ---- collect candidates >= 8-bit (sign+exponent) threshold ----
__global__ void collect_kernel(const unsigned* __restrict__ keysE,
                               const unsigned* __restrict__ keysI,
                               const unsigned* __restrict__ hists,
                               unsigned* __restrict__ counters, unsigned* __restrict__ cand) {
    const int y = blockIdx.y;
    const unsigned* keys = y ? keysI : keysE;
    const int n = y ? N_ITEMS : N_EDGES;
    const unsigned K = y ? K_ITEMS : K_EDGES;
    const unsigned* H = hists + (size_t)y * 256;
    unsigned aboveA;
    unsigned binA = select_digit(H, K, &aboveA);
    const unsigned T = binA << 24;
    unsigned* cd = cand + (size_t)y * 2 * CAND_CAP;

    int i = blockIdx.x * blockDim.x + threadIdx.x;
    int stride = gridDim.x * blockDim.x;
    for (; i < n; i += stride) {
        unsigned k = keys[i];
        if (k >= T) {
            unsigned p = atomicAdd(&counters[y], 1u);   // rare (~1.6k total): fine
            if (p < (unsigned)CAND_CAP) { cd[2 * p] = k; cd[2 * p + 1] = (unsigned)i; }
        }
    }
}

// ---- exact rank among candidates (key desc, index asc); 2 blocks (y) ----
__global__ void final_topk_kernel(const unsigned* __restrict__ cand,
                                  const unsigned* __restrict__ counters,
                                  float* __restrict__ out_topkv, float* __restrict__ out_topki,
                                  float* __restrict__ out_itemv, float* __restrict__ out_itemi) {
    __shared__ unsigned sk[CAND_CAP];
    __shared__ unsigned si[CAND_CAP];
    const int y = blockIdx.x;
    const int K = y ? K_ITEMS : K_EDGES;
    float* outv = y ? out_itemv : out_topkv;
    float* outi = y ? out_itemi : out_topki;
    const unsigned* cd = cand + (size_t)y * 2 * CAND_CAP;
    unsigned m = counters[y];
    if (m > (unsigned)CAND_CAP) m = CAND_CAP;
    for (unsigned i = threadIdx.x; i < m; i += blockDim.x) {
        sk[i] = cd[2 * i];
        si[i] = cd[2 * i + 1];
    }
    __syncthreads();
    for (unsigned i = threadIdx.x; i < m; i += blockDim.x) {
        unsigned ki = sk[i], xi = si[i];
        int r = 0;
        for (unsigned j = 0; j < m; ++j) {
            unsigned kj = sk[j];
            if (kj > ki || (kj == ki && si[j] < xi)) r++;
        }
        if (r < K) {
            outv[r] = funkey(ki);
            outi[r] = (float)xi;
        }
    }
}

extern "C" void kernel_launch(void* const* d_in, const int* in_sizes, int n_in,
                              void* d_out, int out_size, void* d_ws, size_t ws_size,
                              hipStream_t stream) {
    (void)in_sizes; (void)n_in; (void)out_size; (void)ws_size;
    const float* emb    = (const float*)d_in[0];
    const float* W      = (const float*)d_in[1];
    const float* rel    = (const float*)d_in[2];
    const float* noise  = (const float*)d_in[3];
    const int*   eidx   = (const int*)d_in[4];
    const int*   etype  = (const int*)d_in[5];
    const int* head = eidx;
    const int* tail = eidx + N_EDGES;

    float* out        = (float*)d_out;
    float* out_scores = out;
    float* out_topkv  = out + N_EDGES;
    float* out_topki  = out + N_EDGES + K_EDGES;
    float* out_itemv  = out + N_EDGES + 2 * K_EDGES;
    float* out_itemi  = out + N_EDGES + 2 * K_EDGES + K_ITEMS;

    float* ws = (float*)d_ws;
    size_t o = 0;
    float*    proj    = ws + o;               o += (size_t)N_ENTITIES * DIM;
    unsigned* off     = (unsigned*)(ws + o);  o += NSC;          // bucket hist -> scanned in place
    unsigned* bsum    = (unsigned*)(ws + o);  o += 1024;
    u64*      rec2    = (u64*)(ws + o);       o += 2 * (size_t)N_EDGES;   // bucket-major
    u64*      rec3    = (u64*)(ws + o);       o += 2 * (size_t)N_EDGES;   // CSR-ordered
    unsigned* keysE   = (unsigned*)rec2;      // rec2 dead after csr_kernel
    unsigned* keysI   = keysE + N_EDGES;
    unsigned* start   = (unsigned*)(ws + o);  o += N_ENTITIES;
    unsigned* degtot  = (unsigned*)(ws + o);  o += N_ENTITIES;
    float*    logits  = ws + o;               o += N_EDGES;
    float2*   nd      = (float2*)(ws + o);    o += 2 * (size_t)N_ENTITIES;
    float*    sumhead = ws + o;               o += N_ENTITIES;
    float*    sumI    = ws + o;               o += N_ITEMS;      // memset begins
    unsigned* counters= (unsigned*)(ws + o);  o += 2;            // memset ends
    unsigned* histB   = (unsigned*)(ws + o);  o += (size_t)NBLK3 * 512;   // fully overwritten
    unsigned* hists   = (unsigned*)(ws + o);  o += 512;                   // fully overwritten
    unsigned* cand    = (unsigned*)(ws + o);  o += 2 * 2 * CAND_CAP;

    // zero: sumI + counters only (~0.4MB)
    hipMemsetAsync(sumI, 0, ((size_t)N_ITEMS + 2) * 4, stream);
    // pure GEMM
    hipLaunchKernelGGL(proj_kernel, dim3(12500), dim3(256), 0, stream, emb, W, proj);
    // atomic-free CSR build: bucket hist -> scan -> bucket scatter -> per-bucket CSR
    hipLaunchKernelGGL(bhist_kernel, dim3(NB1), dim3(256), 0, stream, head, off);
    hipLaunchKernelGGL(scanA_kernel, dim3(NSC / 256), dim3(256), 0, stream, off, bsum);
    hipLaunchKernelGGL(scanB_kernel, dim3(NSC / 256), dim3(256), 0, stream, bsum, off);
    hipLaunchKernelGGL(bscat_kernel, dim3(NB1), dim3(256), 0, stream,
                       head, tail, etype, off, rec2);
    hipLaunchKernelGGL(csr_kernel, dim3(NBUCK), dim3(256), 0, stream,
                       rec2, off, rec3, start, degtot);
    // CSR main pass (head row amortized; in-register denom/head-sums)
    hipLaunchKernelGGL(node_pass, dim3(N_ENTITIES / 4), dim3(256), 0, stream,
                       (const float4*)proj, (const float4*)rel, rec3, start, degtot,
                       logits, nd, sumhead, sumI);
    // scores + noisy keys + item keys + partial hists (stores only)
    hipLaunchKernelGGL(edge_pass3, dim3(NBLK3), dim3(256), 0, stream,
                       logits, head, nd, noise, sumhead, sumI,
                       out_scores, keysE, keysI, histB);
    // fold partial hists -> hists[512]
    hipLaunchKernelGGL(reduce_hist_kernel, dim3(512), dim3(64), 0, stream, histB, hists);
    // top-k: single 8-bit threshold collect + exact rank
    hipLaunchKernelGGL(collect_kernel, dim3(512, 2), dim3(256), 0, stream,
                       keysE, keysI, hists, counters, cand);
    hipLaunchKernelGGL(final_topk_kernel, dim3(2), dim3(1024), 0, stream,
                       cand, counters, out_topkv, out_topki, out_itemv, out_itemi);
}